// Round 10
// baseline (428.810 us; speedup 1.0000x reference)
//
#include <hip/hip_runtime.h>
#include <hip/hip_bf16.h>
#include <cstdint>
#include <cstddef>

typedef __hip_bfloat16 bf16;
typedef __attribute__((ext_vector_type(8))) short short8;
typedef __attribute__((ext_vector_type(4))) short short4v;
typedef __attribute__((ext_vector_type(4))) float floatx4;

// Problem dims (all tensors float32; gates staged bf16)
#define BB 8
#define SS 4096
#define DIN 256
#define DH 512
#define NCH 256
#define CHUNK 16       // NCH*CHUNK == SS

__device__ __forceinline__ float sh2f(short v) {
    unsigned int u = ((unsigned int)(unsigned short)v) << 16;
    float f; __builtin_memcpy(&f, &u, 4); return f;
}
__device__ __forceinline__ float frcp(float x) { return __builtin_amdgcn_rcpf(x); }
__device__ __forceinline__ short f2sh(float a) {
    bf16 bv = __float2bfloat16(a);
    short sv; __builtin_memcpy(&sv, &bv, 2); return sv;
}

// ---------------- kernel 0: prep = transpose W + clear ticket counters ------
// bx < 2048 : W (f32 [256][512] x4) -> Wt (bf16 [2048][256]), gate-interleaved
//             N: row r = y*128 + g*32 + hh  ->  gate g, h = y*32 + hh.
// bx == 2048: clear the per-pass ticket counters (graph-replay safe).
__global__ __launch_bounds__(256) void prep(
    const float* __restrict__ Wi, const float* __restrict__ Wf,
    const float* __restrict__ Wo, const float* __restrict__ Wz,
    bf16* __restrict__ Wt, unsigned int* __restrict__ Ctr)
{
    const int bx = blockIdx.x;
    const int tid = threadIdx.x;
    if (bx < 2048) {
        int o = bx * 256 + tid;               // 0..524287
        int r = o >> 8;                       // interleaved n index 0..2047
        int k = o & 255;
        int y = r >> 7;                       // h-group 0..15
        int c = r & 127;
        int g = c >> 5;                       // gate 0..3
        int h = y * 32 + (c & 31);            // 0..511
        const float* W = (g == 0) ? Wi : (g == 1) ? Wf : (g == 2) ? Wo : Wz;
        Wt[o] = __float2bfloat16(W[(size_t)k * DH + h]);
    } else {
        if (tid < 8) Ctr[tid] = 0u;
    }
}

// ---------------- kernel 1: GEMM(+x-convert) + act + gates + carries + scan --
__device__ __forceinline__ void load16_lds(const bf16* g, short* l)
{
    __builtin_amdgcn_global_load_lds(
        (const __attribute__((address_space(1))) unsigned int*)g,
        (__attribute__((address_space(3))) unsigned int*)l,
        16, 0, 0);
}

// 1D grid nb*512; XCD-contiguous swizzle (r4/r9-proven: FETCH ~14 MB).
// A-tiles reg-staged from f32 x (convert fused, Xb deleted); B via proven
// global_load_lds from Wt. Tail: ticket-ordered bounded sync — the last nb*8
// finishers run the two-level chunk scan in-kernel (deletes scan_chunks launch).
__global__ __launch_bounds__(256) void gemm_scan(
    const float* __restrict__ X, const bf16* __restrict__ Wt,
    const float* __restrict__ bi, const float* __restrict__ bfv,
    const float* __restrict__ bo, const float* __restrict__ bz,
    bf16* __restrict__ Pi, bf16* __restrict__ Pf,
    bf16* __restrict__ Po, bf16* __restrict__ Pz,
    float* __restrict__ Aa, float* __restrict__ Bca, float* __restrict__ Bna,
    unsigned int* __restrict__ Ctr, int nb, int pass)
{
    // K-loop: 2 x 16 KB staging double-buffer; epilogue reuses the whole
    // buffer as the 128x132(pad) bf16 C-tile; scan reuses it as float scratch.
    __shared__ __align__(16) short smem[128 * 132];   // 33792 B
    __shared__ int s_rank;

    const int cpx = gridDim.x >> 3;
    const int logical = ((int)blockIdx.x & 7) * cpx + ((int)blockIdx.x >> 3);
    const int y  = logical & 15;
    const int m0 = (logical >> 4) * 128;
    const int n0 = y * 128;

    const int tid  = threadIdx.x;
    const int wave = tid >> 6, lane = tid & 63;
    const int wm   = (wave >> 1) * 64, wn = (wave & 1) * 64;
    const int l15  = lane & 15;
    const int q    = lane >> 4;

    floatx4 acc[4][4];
#pragma unroll
    for (int i = 0; i < 4; i++)
#pragma unroll
        for (int j = 0; j < 4; j++) acc[i][j] = (floatx4){0.f, 0.f, 0.f, 0.f};

    const int r_ld = tid >> 2;
    const int c_ld = tid & 3;
    const float* xg0 = X + (size_t)(m0 + r_ld) * DIN + c_ld * 8;
    const float* xg1 = xg0 + (size_t)64 * DIN;
    const bf16* bgp0 = Wt + (size_t)(n0 + r_ld) * DIN + c_ld * 8;
    const bf16* bgp1 = Wt + (size_t)(n0 + 64 + r_ld) * DIN + c_ld * 8;

    // Pipeline (fenced per rule #18; counted vmcnt per r9-proven discipline):
    //   issue A(k+1) f32 loads [4] + B(k+1) gload_lds [2]
    //   vmcnt(6): B(k) landed  -> barrier -> ds_read+MFMA(k)
    //   vmcnt(2): A(k+1) in regs (B(k+1) still in flight) -> cvt+ds_write
    //   lgkmcnt(0) -> barrier (buf cur free; A(k+1) staged)
    float4 a00, a01, a10, a11;
#define ISSUE_A(K0)                                                   \
    do {                                                              \
        a00 = *(const float4*)(xg0 + (K0));                           \
        a01 = *(const float4*)(xg0 + (K0) + 4);                       \
        a10 = *(const float4*)(xg1 + (K0));                           \
        a11 = *(const float4*)(xg1 + (K0) + 4);                       \
    } while (0)
#define ISSUE_B(K0, Bb)                                               \
    do {                                                              \
        load16_lds(bgp0 + (K0), &(Bb)[tid * 8]);                      \
        load16_lds(bgp1 + (K0), &(Bb)[2048 + tid * 8]);               \
    } while (0)
#define WRITE_A(Ab)                                                   \
    do {                                                              \
        bf16 t0[8] = {__float2bfloat16(a00.x), __float2bfloat16(a00.y), \
                      __float2bfloat16(a00.z), __float2bfloat16(a00.w), \
                      __float2bfloat16(a01.x), __float2bfloat16(a01.y), \
                      __float2bfloat16(a01.z), __float2bfloat16(a01.w)};\
        *(short8*)&(Ab)[tid * 8] = *(const short8*)t0;                \
        bf16 t1[8] = {__float2bfloat16(a10.x), __float2bfloat16(a10.y), \
                      __float2bfloat16(a10.z), __float2bfloat16(a10.w), \
                      __float2bfloat16(a11.x), __float2bfloat16(a11.y), \
                      __float2bfloat16(a11.z), __float2bfloat16(a11.w)};\
        *(short8*)&(Ab)[2048 + tid * 8] = *(const short8*)t1;         \
    } while (0)

    // prologue: stage tile 0
    ISSUE_A(0);
    ISSUE_B(0, smem + 4096);
    asm volatile("s_waitcnt vmcnt(2)" ::: "memory");   // A(0) landed
    WRITE_A(smem);
    asm volatile("s_waitcnt lgkmcnt(0)" ::: "memory");
    __builtin_amdgcn_s_barrier();                      // A-buf0 ready

#pragma unroll
    for (int k = 0; k < 8; k++) {
        const int cur = k & 1;
        short* Ab = smem + cur * 8192;
        short* Bb = Ab + 4096;
        short* An = smem + (cur ^ 1) * 8192;
        short* Bn = An + 4096;
        if (k < 7) {
            ISSUE_A((k + 1) * 32);
            ISSUE_B((k + 1) * 32, Bn);
            asm volatile("s_waitcnt vmcnt(6)" ::: "memory");  // B(k) landed
        } else {
            asm volatile("s_waitcnt vmcnt(0)" ::: "memory");
        }
        __builtin_amdgcn_s_barrier();          // all waves' B(k) landed

        short8 af[4], bfr[4];
#pragma unroll
        for (int ti = 0; ti < 4; ti++)
            af[ti] = *(const short8*)&Ab[(wm + ti * 16 + l15) * 32 + q * 8];
#pragma unroll
        for (int tj = 0; tj < 4; tj++)
            bfr[tj] = *(const short8*)&Bb[(wn + tj * 16 + l15) * 32 + q * 8];
#pragma unroll
        for (int ti = 0; ti < 4; ti++)
#pragma unroll
            for (int tj = 0; tj < 4; tj++)
                acc[ti][tj] = __builtin_amdgcn_mfma_f32_16x16x32_bf16(
                    af[ti], bfr[tj], acc[ti][tj], 0, 0, 0);

        if (k < 7) {
            asm volatile("s_waitcnt vmcnt(2)" ::: "memory");  // A(k+1) in regs
            WRITE_A(An);
        }
        asm volatile("s_waitcnt lgkmcnt(0)" ::: "memory");
        __builtin_amdgcn_s_barrier();          // buf cur free; A(k+1) staged
    }
#undef ISSUE_A
#undef ISSUE_B
#undef WRITE_A

    // -------- epilogue: bias + activation -> bf16 -> LDS C-tile [m][132] ----
#pragma unroll
    for (int ti = 0; ti < 4; ti++) {
        const int mrow = wm + ti * 16 + q * 4;       // tile-local row
#pragma unroll
        for (int tj = 0; tj < 4; tj++) {
            const int cb = wn + tj * 16;             // wave-uniform col base
            const int g  = cb >> 5;                  // gate 0..3 (uniform)
            const int c  = cb + l15;                 // tile-local col
            const float* bp = (g == 0) ? bi : (g == 1) ? bfv
                            : (g == 2) ? bo : bz;
            const float bsv = bp[y * 32 + (c & 31)];
#pragma unroll
            for (int r = 0; r < 4; r++) {
                const float v = acc[ti][tj][r] + bsv;
                float a;
                if (g == 0 || g == 1) {
                    a = __expf(fminf(fmaxf(v, -20.f), 0.f));     // exp(clip)
                } else if (g == 2) {
                    a = frcp(1.f + __expf(-v));                  // sigmoid
                } else {
                    a = 1.f - 2.f * frcp(__expf(2.f * v) + 1.f); // tanh
                }
                smem[(mrow + r) * 132 + c] = f2sh(a);
            }
        }
    }
    __syncthreads();

    const int bidx = m0 / SS;            // pass-local batch (SS % 128 == 0)

    // -------- coalesced copy-out: LDS -> gate planes, 8 B per lane ----------
    {
        const int cp  = (tid & 31) * 4;              // col base (4 cols, 1 gate)
        const int g2  = cp >> 5;
        const int hb  = y * 32 + (cp & 31);
        bf16* pl = ((g2 == 0) ? Pi : (g2 == 1) ? Pf : (g2 == 2) ? Po : Pz) + hb;
        const int r0 = tid >> 5;
#pragma unroll
        for (int t = 0; t < 16; t++) {
            const int row = t * 8 + r0;
            short4v v = *(const short4v*)&smem[row * 132 + cp];
            *(short4v*)(pl + (size_t)(m0 + row) * DH) = v;
        }
    }

    // -------- fused chunk-carry: 256 chains (8 chunks x 32 h), f32 scan -----
    {
        const int hh = tid & 31;
        const int ch = tid >> 5;                     // chunk (16 rows) in tile
        float A = 1.f, Bc = 0.f, Bn = 0.f;
        const short* base = &smem[(ch * CHUNK) * 132];
#pragma unroll
        for (int s = 0; s < CHUNK; s++) {
            const short* rp = base + s * 132;
            const float iv = sh2f(rp[hh]);
            const float f  = sh2f(rp[32 + hh]);
            const float zv = sh2f(rp[96 + hh]);
            Bc = fmaf(f, Bc, iv * zv);
            Bn = fmaf(f, Bn, iv);
            A *= f;
        }
        const int ch_g = ((m0 % SS) >> 4) + ch;      // batch-local chunk 0..255
        const int hgl  = y * 32 + hh;
        const size_t cidx = (size_t)(ch_g * nb + bidx) * DH + hgl;
        Aa[cidx] = A; Bca[cidx] = Bc; Bna[cidx] = Bn;
    }

    // -------- publish + bounded tail sync (ticket-ordered, <=64 spinners) ---
    // __syncthreads drains each wave's vmcnt (stores in L2); tid0's
    // threadfence (agent release) flushes L2 -> carries globally visible.
    __syncthreads();
    if (tid == 0) {
        __threadfence();
        unsigned int old = __hip_atomic_fetch_add(
            &Ctr[pass], 1u, __ATOMIC_RELAXED, __HIP_MEMORY_SCOPE_AGENT);
        s_rank = (int)old - (int)(gridDim.x - nb * 8);
    }
    __syncthreads();
    const int rank = s_rank;
    if (rank < 0) return;            // not among the last nb*8 finishers

    // Bounded spin: <=64 blocks, relaxed agent polls, duration = dispatch
    // tail only (every block increments BEFORE spinning; spinners < slots
    // -> stragglers always get CUs -> deadlock-free for any dispatch order).
    if (tid == 0) {
        while (__hip_atomic_load(&Ctr[pass], __ATOMIC_RELAXED,
                                 __HIP_MEMORY_SCOPE_AGENT) < gridDim.x)
            __builtin_amdgcn_s_sleep(32);
    }
    __syncthreads();
    __threadfence();                 // acquire: invalidate L1/L2 (1 per wave)

    // -------- two-level scan over chunk carries (ex-scan_chunks, in-place) --
    {
        float* sA  = (float*)smem;           // [4][64] scratch (C-tile dead)
        float* sBc = sA + 256;
        float* sBn = sBc + 256;
        const int l  = tid & 63;
        const int t  = rank * 64 + l;        // chain id (b*512+h)
        const int s  = tid >> 6;             // segment 0..3
        const int stride = nb * DH;
        const int SEG = NCH / 4;             // 64

        float A = 1.f, Bc = 0.f, Bn = 0.f;
        for (int k = 0; k < SEG; k++) {
            const size_t cidx = (size_t)(s * SEG + k) * stride + t;
            const float a  = Aa[cidx];
            const float bc = Bca[cidx];
            const float bn = Bna[cidx];
            Bc = fmaf(a, Bc, bc);
            Bn = fmaf(a, Bn, bn);
            A *= a;
        }
        sA[s * 64 + l] = A; sBc[s * 64 + l] = Bc; sBn[s * 64 + l] = Bn;
        __syncthreads();

        float c = 0.f, n = 1.f;
#pragma unroll
        for (int s2 = 0; s2 < 3; s2++) {
            if (s2 < s) {
                const float a  = sA[s2 * 64 + l];
                const float nc = fmaf(a, c, sBc[s2 * 64 + l]);
                n = fmaf(a, n, sBn[s2 * 64 + l]);
                c = nc;
            }
        }
        for (int k = 0; k < SEG; k++) {
            const size_t cidx = (size_t)(s * SEG + k) * stride + t;
            const float a  = Aa[cidx];
            const float bc = Bca[cidx];
            const float bn = Bna[cidx];
            Aa[cidx] = c; Bca[cidx] = n;     // state BEFORE chunk k
            const float nc = fmaf(a, c, bc);
            n = fmaf(a, n, bn);
            c = nc;
        }
    }
}

// ---------------- kernel 2: replay chunk with true init, emit h (f32) --------
// 2 chunks/block, 4 h/thread -> NCH/2 * nb = 1024 blocks (16 waves/CU).
__global__ __launch_bounds__(256) void scan_emit(
    const bf16* __restrict__ Pi, const bf16* __restrict__ Pf,
    const bf16* __restrict__ Po, const bf16* __restrict__ Pz,
    const float* __restrict__ Cs, const float* __restrict__ Ns,
    float* __restrict__ out, int nb)
{
    const int tid = threadIdx.x;
    const int ch  = blockIdx.x * 2 + (tid >> 7);
    const int b   = blockIdx.y;
    const int hg  = (tid & 127) * 4;
    const size_t base = ((size_t)(b * SS + ch * CHUNK)) * DH + hg;
    const size_t cidx = (size_t)(ch * nb + b) * DH + hg;

    float c[4], n[4];
    *(floatx4*)c = *(const floatx4*)(Cs + cidx);
    *(floatx4*)n = *(const floatx4*)(Ns + cidx);

#pragma unroll 4
    for (int s = 0; s < CHUNK; s++) {
        const size_t o = base + (size_t)s * DH;
        short4v i4 = *(const short4v*)(Pi + o);
        short4v f4 = *(const short4v*)(Pf + o);
        short4v o4 = *(const short4v*)(Po + o);
        short4v z4 = *(const short4v*)(Pz + o);
        float h[4];
#pragma unroll
        for (int j = 0; j < 4; j++) {
            const float f  = sh2f(f4[j]);
            const float iv = sh2f(i4[j]);
            const float ov = sh2f(o4[j]);
            const float zv = sh2f(z4[j]);
            c[j] = fmaf(f, c[j], iv * zv);
            n[j] = fmaf(f, n[j], iv);
            h[j] = ov * c[j] * frcp(n[j] + 1e-6f);
        }
        *(floatx4*)(out + o) = *(floatx4*)h;
    }
}

// ---------------- launch -----------------------------------------------------
extern "C" void kernel_launch(void* const* d_in, const int* in_sizes, int n_in,
                              void* d_out, int out_size, void* d_ws, size_t ws_size,
                              hipStream_t stream)
{
    const float* x   = (const float*)d_in[0];
    const float* Wi  = (const float*)d_in[1];
    const float* bi  = (const float*)d_in[2];
    const float* Wf  = (const float*)d_in[3];
    const float* bfv = (const float*)d_in[4];
    const float* Wo  = (const float*)d_in[5];
    const float* bo  = (const float*)d_in[6];
    const float* Wz  = (const float*)d_in[7];
    const float* bz  = (const float*)d_in[8];
    float* out = (float*)d_out;

    // ws-adaptive: nb batches per pass (no Xb anymore — x read f32 in-gemm).
    int nb = BB;
    while (nb > 1) {
        size_t need = (1u << 20)                         // Wt
                    + 4 * (size_t)nb * SS * DH * 2       // Pi,Pf,Po,Pz
                    + 3 * (size_t)NCH * nb * DH * 4      // Aa,Bca,Bna
                    + 64;                                // Ctr
        if (need <= ws_size) break;
        nb >>= 1;
    }

    const size_t plane = (size_t)nb * SS * DH;
    bf16* Wt = (bf16*)d_ws;
    bf16* Pi = (bf16*)((char*)d_ws + (1u << 20));
    bf16* Pf = Pi + plane;
    bf16* Po = Pf + plane;
    bf16* Pz = Po + plane;
    float* Aa  = (float*)(Pz + plane);
    float* Bca = Aa  + (size_t)NCH * nb * DH;
    float* Bna = Bca + (size_t)NCH * nb * DH;
    unsigned int* Ctr = (unsigned int*)(Bna + (size_t)NCH * nb * DH);

    prep<<<2049, 256, 0, stream>>>(Wi, Wf, Wo, Wz, Wt, Ctr);

    int pass = 0;
    for (int b0 = 0; b0 < BB; b0 += nb, pass++) {
        const float* Xsrc = x   + (size_t)b0 * SS * DIN;
        float*       Ob   = out + (size_t)b0 * SS * DH;
        gemm_scan<<<nb * 512, 256, 0, stream>>>(
            Xsrc, Wt, bi, bfv, bo, bz, Pi, Pf, Po, Pz,
            Aa, Bca, Bna, Ctr, nb, pass);
        scan_emit<<<dim3(NCH / 2, nb), 256, 0, stream>>>(
            Pi, Pf, Po, Pz, Aa, Bca, Ob, nb);
    }
}